// Round 2
// baseline (730.930 us; speedup 1.0000x reference)
//
#include <hip/hip_runtime.h>

// Problem constants: N=500000 (from in_sizes), D=256, K=512, OUT=32
#define DFEAT 256
#define KINST 512
#define OUTC  32
#define CHUNK 4096          // points per block for hist/scatter kernels
#define BUCKET_CHUNK 2048   // bucket indices staged in LDS per gather iteration

// ---------- Phase 1: per-block histogram + streaming coord sums ----------
// Coords are read COALESCED here (contiguous chunk) instead of gathered
// randomly in the big kernel. Per-block partial sums via LDS float atomics,
// one global atomic per (block,bin). Per-block hist also written to global
// so the scatter pass needs no second histogram and no cursor atomics.
__global__ __launch_bounds__(256) void hist_coords_kernel(
        const int* __restrict__ ids, const float* __restrict__ coords,
        int* __restrict__ counts, float* __restrict__ csum,
        int* __restrict__ blockhist, int n) {
    __shared__ int hist[KINST];
    __shared__ float sx[KINST], sy[KINST], sz[KINST];
    int start = blockIdx.x * CHUNK;
    int len = n - start;
    if (len > CHUNK) len = CHUNK;
    for (int b = threadIdx.x; b < KINST; b += 256) {
        hist[b] = 0; sx[b] = 0.f; sy[b] = 0.f; sz[b] = 0.f;
    }
    __syncthreads();
    for (int l = threadIdx.x; l < len; l += 256) {
        int id = ids[start + l];
        if (id >= 0) {
            long p = (long)(start + l) * 3;
            float x = coords[p + 0];
            float y = coords[p + 1];
            float z = coords[p + 2];
            atomicAdd(&hist[id], 1);     // LDS atomic
            atomicAdd(&sx[id], x);       // ds_add_f32
            atomicAdd(&sy[id], y);
            atomicAdd(&sz[id], z);
        }
    }
    __syncthreads();
    for (int b = threadIdx.x; b < KINST; b += 256) {
        int c = hist[b];
        blockhist[blockIdx.x * KINST + b] = c;
        if (c) {
            atomicAdd(&counts[b], c);
            atomicAdd(&csum[b * 3 + 0], sx[b]);
            atomicAdd(&csum[b * 3 + 1], sy[b]);
            atomicAdd(&csum[b * 3 + 2], sz[b]);
        }
    }
}

// ---------- Phase 2: scan + per-(block,bin) bases + centroids ----------
// One block, 512 threads (thread t owns bin t). blockhist/blockbase accesses
// are coalesced (contiguous 512 ints per iteration).
__global__ void scan_kernel(const int* __restrict__ counts,
                            const float* __restrict__ csum,
                            int* __restrict__ offsets,
                            const int* __restrict__ blockhist,
                            int* __restrict__ blockbase,
                            float* __restrict__ cent_out, int nblk) {
    __shared__ int s[KINST];
    int t = threadIdx.x;
    int c = counts[t];
    s[t] = c;
    __syncthreads();
    for (int off = 1; off < KINST; off <<= 1) {
        int add = (t >= off) ? s[t - off] : 0;
        __syncthreads();
        s[t] += add;
        __syncthreads();
    }
    int excl = s[t] - c;   // exclusive prefix
    offsets[t] = excl;

    float inv = 1.0f / (float)(c > 1 ? c : 1);
    cent_out[t * 3 + 0] = csum[t * 3 + 0] * inv;
    cent_out[t * 3 + 1] = csum[t * 3 + 1] * inv;
    cent_out[t * 3 + 2] = csum[t * 3 + 2] * inv;

    int base = excl;
    for (int blk = 0; blk < nblk; ++blk) {
        blockbase[blk * KINST + t] = base;
        base += blockhist[blk * KINST + t];
    }
}

// ---------- Phase 3: single-pass scatter (no global cursor atomics) ----------
__global__ __launch_bounds__(256) void scatter_kernel(
        const int* __restrict__ ids, const int* __restrict__ blockbase,
        int* __restrict__ bucket, int n) {
    __shared__ int bases[KINST];
    __shared__ int lcur[KINST];
    int start = blockIdx.x * CHUNK;
    int len = n - start;
    if (len > CHUNK) len = CHUNK;
    for (int b = threadIdx.x; b < KINST; b += 256) {
        bases[b] = blockbase[blockIdx.x * KINST + b];
        lcur[b] = 0;
    }
    __syncthreads();
    for (int l = threadIdx.x; l < len; l += 256) {
        int id = ids[start + l];
        if (id >= 0) {
            int w = atomicAdd(&lcur[id], 1);        // LDS atomic
            bucket[bases[id] + w] = start + l;
        }
    }
}

// ---------- Phase 4: gather + mean (features) + fused MLP ----------
// One block per instance, 512 threads = 8 waves. Each wave reads whole 1 KB
// feature rows (64 x float4, coalesced), 4 rows in flight per wave for
// latency hiding. MLP runs in the epilogue on the in-LDS embedding.
__global__ __launch_bounds__(512) void gather_mlp_kernel(
        const float4* __restrict__ feat4,
        const int* __restrict__ bucket,
        const int* __restrict__ offsets,
        const int* __restrict__ counts,
        const float* __restrict__ W1, const float* __restrict__ W2,
        const float* __restrict__ W3, const float* __restrict__ b3,
        float* __restrict__ emb_out, float* __restrict__ mlp_out) {
    __shared__ int bl[BUCKET_CHUNK];
    __shared__ float red[2048];
    __shared__ float e[DFEAT];
    __shared__ float h1[64];
    __shared__ float h2[64];

    int k   = blockIdx.x;
    int off = offsets[k];
    int cnt = counts[k];

    int sub = threadIdx.x >> 6;   // wave id, 0..7
    int f4  = threadIdx.x & 63;   // float4 column within the row

    float a0x=0.f,a0y=0.f,a0z=0.f,a0w=0.f;
    float a1x=0.f,a1y=0.f,a1z=0.f,a1w=0.f;
    float a2x=0.f,a2y=0.f,a2z=0.f,a2w=0.f;
    float a3x=0.f,a3y=0.f,a3z=0.f,a3w=0.f;

    for (int base = 0; base < cnt; base += BUCKET_CHUNK) {
        int chunk = cnt - base;
        if (chunk > BUCKET_CHUNK) chunk = BUCKET_CHUNK;
        for (int t = threadIdx.x; t < chunk; t += 512) bl[t] = bucket[off + base + t];
        __syncthreads();

        // 4 independent 1 KB rows in flight per wave (64 B/lane outstanding)
        int i = sub;
        for (; i + 24 < chunk; i += 32) {
            int r0 = bl[i];
            int r1 = bl[i + 8];
            int r2 = bl[i + 16];
            int r3 = bl[i + 24];
            float4 v0 = feat4[(long)r0 * 64 + f4];
            float4 v1 = feat4[(long)r1 * 64 + f4];
            float4 v2 = feat4[(long)r2 * 64 + f4];
            float4 v3 = feat4[(long)r3 * 64 + f4];
            a0x += v0.x; a0y += v0.y; a0z += v0.z; a0w += v0.w;
            a1x += v1.x; a1y += v1.y; a1z += v1.z; a1w += v1.w;
            a2x += v2.x; a2y += v2.y; a2z += v2.z; a2w += v2.w;
            a3x += v3.x; a3y += v3.y; a3z += v3.z; a3w += v3.w;
        }
        for (; i < chunk; i += 8) {
            int r = bl[i];
            float4 v = feat4[(long)r * 64 + f4];
            a0x += v.x; a0y += v.y; a0z += v.z; a0w += v.w;
        }
        __syncthreads();   // protect bl before next staging
    }

    a0x += a1x + a2x + a3x;
    a0y += a1y + a2y + a3y;
    a0z += a1z + a2z + a3z;
    a0w += a1w + a2w + a3w;

    float inv = 1.0f / (float)(cnt > 1 ? cnt : 1);

    // feature reduction across the 8 waves
    red[threadIdx.x * 4 + 0] = a0x;
    red[threadIdx.x * 4 + 1] = a0y;
    red[threadIdx.x * 4 + 2] = a0z;
    red[threadIdx.x * 4 + 3] = a0w;
    __syncthreads();
    if (sub == 0) {
        float tx = 0.f, ty = 0.f, tz = 0.f, tw = 0.f;
        #pragma unroll
        for (int s = 0; s < 8; s++) {
            int b = (s * 64 + f4) * 4;
            tx += red[b + 0]; ty += red[b + 1]; tz += red[b + 2]; tw += red[b + 3];
        }
        float4 o;
        o.x = tx * inv; o.y = ty * inv; o.z = tz * inv; o.w = tw * inv;
        ((float4*)emb_out)[(long)k * 64 + f4] = o;
        e[f4 * 4 + 0] = o.x; e[f4 * 4 + 1] = o.y;
        e[f4 * 4 + 2] = o.z; e[f4 * 4 + 3] = o.w;
    }
    __syncthreads();

    // fused MLP on the in-LDS embedding (wave 0 only; overlaps with the
    // co-resident block's memory phase on the same CU)
    int j = threadIdx.x;
    if (j < 64) {
        float acc = 0.f;
        #pragma unroll 8
        for (int d = 0; d < DFEAT; d++) acc += e[d] * W1[d * 64 + j];
        h1[j] = fmaxf(acc, 0.f);
    }
    __syncthreads();
    if (j < 64) {
        float acc = 0.f;
        #pragma unroll 8
        for (int d = 0; d < 64; d++) acc += h1[d] * W2[d * 64 + j];
        h2[j] = fmaxf(acc, 0.f);
    }
    __syncthreads();
    if (j < OUTC) {
        float o = b3[j];
        #pragma unroll 8
        for (int d = 0; d < 64; d++) o += h2[d] * W3[d * OUTC + j];
        mlp_out[k * OUTC + j] = o;
    }
}

extern "C" void kernel_launch(void* const* d_in, const int* in_sizes, int n_in,
                              void* d_out, int out_size, void* d_ws, size_t ws_size,
                              hipStream_t stream) {
    const float* features = (const float*)d_in[0];
    const float* coords   = (const float*)d_in[1];
    const int*   ids      = (const int*)d_in[2];
    // d_in[3] = num_instances (K=512, hardcoded)
    const float* W1 = (const float*)d_in[4];
    const float* W2 = (const float*)d_in[5];
    const float* W3 = (const float*)d_in[6];
    const float* b3 = (const float*)d_in[7];

    int n = in_sizes[2];   // number of points
    int nblk = (n + CHUNK - 1) / CHUNK;   // 123 for N=500k

    float* out      = (float*)d_out;
    float* emb_out  = out;                          // [512, 256]
    float* cent_out = out + (long)KINST * DFEAT;    // [512, 3]
    float* mlp_out  = cent_out + (long)KINST * 3;   // [512, 32]

    // workspace layout (poisoned 0xAA each call -> zero what we accumulate into)
    char* ws = (char*)d_ws;
    int*   counts    = (int*)(ws + 0);        // 512*4  = 2048
    float* csum      = (float*)(ws + 2048);   // 512*12 = 6144
    int*   offsets   = (int*)(ws + 8192);     // 512*4  = 2048
    int*   blockhist = (int*)(ws + 10240);                       // nblk*2048
    int*   blockbase = (int*)(ws + 10240 + (long)nblk * 2048);   // nblk*2048
    int*   bucket    = (int*)(ws + 10240 + (long)nblk * 4096);   // n*4

    hipMemsetAsync(d_ws, 0, 8192, stream);   // zero counts + csum

    hist_coords_kernel<<<nblk, 256, 0, stream>>>(ids, coords, counts, csum,
                                                 blockhist, n);
    scan_kernel<<<1, KINST, 0, stream>>>(counts, csum, offsets, blockhist,
                                         blockbase, cent_out, nblk);
    scatter_kernel<<<nblk, 256, 0, stream>>>(ids, blockbase, bucket, n);
    gather_mlp_kernel<<<KINST, 512, 0, stream>>>((const float4*)features, bucket,
                                                 offsets, counts,
                                                 W1, W2, W3, b3,
                                                 emb_out, mlp_out);
}